// Round 4
// baseline (986.483 us; speedup 1.0000x reference)
//
#include <hip/hip_runtime.h>
#include <hip/hip_cooperative_groups.h>
#include <math.h>

namespace cg = cooperative_groups;

#define SHEET 160
#define LTOT (SHEET*SHEET)          // 25600
#define F_AFF 450
#define F_LAT 625
#define N_ITERS 10
#define IN_HW 174                   // SHEET + AFF_K - 1
#define HOMEO 0.02f
#define PI_D 3.14159265358979323846

// ---- persistent tile geometry: 5 rows x 20 cols of locations per block ----
#define BH 5
#define BW 20
#define LOCS 100                    // locations per block
#define NW 10                       // waves per block (each owns 10 locations)
#define BLK 640
#define GRID 256                    // (160/5) * (160/20) = 32*8 -> 1 block/CU
#define COLS_T (SHEET/BW)           // 8

#define EH 53                       // BH + 48 E-field rows
#define EWH 35                      // (BW+48)/2 + 1 pad (parity-half width)
#define EP_HALF (EH*EWH)            // 1855
#define EP_N (2*EP_HALF)            // 3710
#define LW 76                       // 72 data cols padded to 76 (16B-aligned rows)
#define LH 57                       // BH + 52
#define LT_N (LH*LW)                // 4332

// ---- workspace layout (float offsets) ----
#define WS_B0   0
#define WS_B1   LTOT
#define WS_LM   (2*LTOT)
#define WS_PART (3*LTOT)            // GRID floats

__device__ __forceinline__ float wred(float v) {
    #pragma unroll
    for (int m = 32; m > 0; m >>= 1) v += __shfl_xor(v, m, 64);
    return v;
}

__device__ __forceinline__ unsigned f2bf(float f) {   // RNE float->bf16 bits
    unsigned u = __float_as_uint(f);
    return (u + 0x7FFFu + ((u >> 16) & 1u)) >> 16;
}

__global__ __launch_bounds__(BLK, 3) void k_main(
    const float* __restrict__ x, const float* __restrict__ rfs,
    const float* __restrict__ latw, const float* __restrict__ ada,
    float* __restrict__ out, float* __restrict__ ws)
{
    __shared__ float Lt[LT_N];
    __shared__ float Ep[EP_N];       // E field / LM tile / reduction scratch
    __shared__ float aff_s[LOCS];
    __shared__ float isum_s[LOCS];
    __shared__ float lm_s[LOCS];
    __shared__ float part_s[NW];

    cg::grid_group grid = cg::this_grid();

    const int tid  = threadIdx.x;
    const int w    = tid >> 6, lane = tid & 63;
    const int b    = blockIdx.x;
    const int i0   = (b / COLS_T) * BH;
    const int j0   = (b % COLS_T) * BW;

    // wave w owns locations li = w*10+s : r = w>>1 (const), cc = (w&1)*10+s
    const int wr    = w >> 1;
    const int wc0   = (w & 1) * 10;
    const int lbase = (i0 + wr) * SHEET + j0 + wc0;              // + s
    const int gb0   = wr * EWH + (w & 1) * 5;                    // + (s&1)*EP_HALF + (s>>1)

    // ================= prologue: constants =================
    // sre[25], normalized (every thread computes identically)
    float sreg[25];
    {
        float ssum = 0.f;
        #pragma unroll
        for (int q = 0; q < 25; ++q) {
            int u = q / 5, v = q % 5;
            int rr = (u-2)*(u-2) + (v-2)*(v-2);
            float val = 0.f;
            if (rr <= 6) {                                       // d < 2.5
                double dd = sqrt((double)rr);
                float rc = (float)cos(fmin(dd/5.0, 1.0) * (PI_D*0.5));
                val = rc * rc;
            }
            sreg[q] = val; ssum += val;
        }
        #pragma unroll
        for (int q = 0; q < 25; ++q) sreg[q] /= ssum;
    }

    // lateral lri (raw) + gather offsets, f = it*64 + lane
    float lriL[10]; int offL[10];
    {
        float lmax = 0.f;
        #pragma unroll
        for (int it = 0; it < 10; ++it) {
            int f = it*64 + lane;
            float lv = 0.f; int off = 0;
            if (f < F_LAT) {
                int dy = f / 25, dx = f - 25*dy;
                int rr = (dy-12)*(dy-12) + (dx-12)*(dx-12);
                if (rr <= 156) {                                  // d < 12.5
                    double dd = sqrt((double)rr);
                    float rc = (float)cos(fmin(dd/25.0, 1.0) * (PI_D*0.5));
                    float base = rc * rc;
                    float inh = 0.f;
                    if (rr <= 1) {                                // d < 1.25
                        float ri = (float)cos(fmin(dd/2.5, 1.0) * (PI_D*0.5));
                        inh = ri * ri;
                    }
                    lv = base * (1.f - inh);
                }
                off = dy * (2*EWH) + dx;
            }
            lriL[it] = lv; offL[it] = off;
            lmax = fmaxf(lmax, lv);
        }
        // block max via Ep scratch (pad to 1024)
        Ep[tid] = lmax;
        if (tid < 1024 - BLK) Ep[BLK + tid] = 0.f;
        __syncthreads();
        #pragma unroll
        for (int s = 512; s > 0; s >>= 1) {
            if (tid < s) Ep[tid] = fmaxf(Ep[tid], Ep[tid + s]);
            __syncthreads();
        }
        const float lri_max = Ep[0];
        __syncthreads();
        #pragma unroll
        for (int it = 0; it < 10; ++it) lriL[it] /= lri_max;
    }

    // afferent env + x-offsets, f = it*64 + lane
    float envA[8]; int offA[8];
    #pragma unroll
    for (int it = 0; it < 8; ++it) {
        int f = it*64 + lane;
        float ev = 0.f; int off = 0;
        if (f < F_AFF) {
            int c = f / 225, r0 = f - 225*c;
            int kh = r0 / 15, kw = r0 - 15*kh;
            int rr = (kh-7)*(kh-7) + (kw-7)*(kw-7);
            if (rr <= 56) {                                       // d < 7.5
                double dd = sqrt((double)rr);
                float rc = (float)cos(fmin(dd/15.0, 1.0) * (PI_D*0.5));
                ev = rc * rc;
            }
            off = c * (IN_HW*IN_HW) + kh * IN_HW + kw;
        }
        envA[it] = ev; offA[it] = off;
    }

    // ===== afferent pass + lateral weight load/pack (weights persist in regs) =====
    unsigned wpk[10][5];
    #pragma unroll
    for (int s = 0; s < 10; ++s) {
        const int l  = lbase + s;
        const int ir = i0 + wr, jc = j0 + wc0 + s;
        // afferent dot
        {
            const float* rrow = rfs + (size_t)l * F_AFF;
            const int xbase = ir * IN_HW + jc;
            float dot = 0.f, sum = 0.f;
            #pragma unroll
            for (int it = 0; it < 8; ++it) {
                int f  = it*64 + lane;
                int fc = (f < F_AFF) ? f : 0;
                float rv = rrow[fc];
                if (f >= F_AFF) rv = 0.f;
                float xv = x[xbase + offA[it]];
                dot = fmaf(xv * envA[it], rv, dot);
                sum += rv;
            }
            dot = wred(dot); sum = wred(sum);
            if (lane == 0) {
                float a = dot / sum;
                out[l] = 45.0f * a;                      // raw_aff
                float af = a - ada[l];
                aff_s[wc0 + s + wr*0 + (w&1)*0 + (w>>1)*0 + (w*10 - w*10) + (w*10) + s - s - wc0] = 0.f; // placeholder avoided below
            }
            // (aff_s write done cleanly below to keep index simple)
            if (lane == 0) {
                float a = dot / sum;
                float af = a - ada[l];
                aff_s[w*10 + s] = af;
                ws[WS_B0 + l]   = fmaxf(af, 0.f);        // lat_0 = relu(aff)
                lm_s[w*10 + s]  = 0.f;
            }
        }
        // lateral weights: load fp32, exact sum, pack bf16 * lri
        {
            const float* wrow = latw + (size_t)l * F_LAT;
            float tmp[10]; float sum = 0.f;
            #pragma unroll
            for (int it = 0; it < 10; ++it) {
                int f  = it*64 + lane;
                int fc = (f < F_LAT) ? f : 0;
                float wv = wrow[fc];
                if (f >= F_LAT) wv = 0.f;
                sum += wv;
                tmp[it] = wv * lriL[it];
            }
            sum = wred(sum);
            if (lane == 0) isum_s[w*10 + s] = 1.0f / sum;
            #pragma unroll
            for (int k = 0; k < 5; ++k)
                wpk[s][k] = f2bf(tmp[2*k]) | (f2bf(tmp[2*k+1]) << 16);
        }
    }
    __threadfence();
    grid.sync();

    // ================= 10 lateral iterations =================
    for (int t = 0; t < N_ITERS; ++t) {
        const float* src = ws + ((t & 1) ? WS_B1 : WS_B0);
        float* dst = (t == N_ITERS-1) ? (out + LTOT)
                                      : (ws + ((t & 1) ? WS_B0 : WS_B1));

        // stage L tile (pad = HOMEO)
        for (int idx = tid; idx < LT_N; idx += BLK) {
            int r = idx / LW, c = idx - r * LW;
            int y  = i0 + r - 26;
            int xx = j0 + c - 26;
            float v = HOMEO;
            if (c < 72 && (unsigned)y < SHEET && (unsigned)xx < SHEET) v = src[y*SHEET + xx];
            Lt[idx] = v;
        }
        __syncthreads();

        // 5x5 conv -> E field (4-wide register blocked, parity-split store)
        for (int qi = tid; qi < EH * 17; qi += BLK) {
            int yy = qi / 17, q = qi - yy * 17;
            int x0 = q * 4;
            float a0 = 0.f, a1 = 0.f, a2 = 0.f, a3 = 0.f;
            #pragma unroll
            for (int u = 0; u < 5; ++u) {
                const float* row = &Lt[(yy + u) * LW + x0];
                float ra[8];
                #pragma unroll
                for (int v = 0; v < 8; ++v) ra[v] = row[v];
                #pragma unroll
                for (int v = 0; v < 5; ++v) {
                    float sv = sreg[u*5 + v];
                    a0 = fmaf(ra[v],     sv, a0);
                    a1 = fmaf(ra[v + 1], sv, a1);
                    a2 = fmaf(ra[v + 2], sv, a2);
                    a3 = fmaf(ra[v + 3], sv, a3);
                }
            }
            int yg = i0 - 24 + yy;
            bool yok = (unsigned)yg < SHEET;
            int xg = j0 - 24 + x0;
            float v0 = (yok && (unsigned)(xg    ) < SHEET) ? a0 : HOMEO;
            float v1 = (yok && (unsigned)(xg + 1) < SHEET) ? a1 : HOMEO;
            float v2 = (yok && (unsigned)(xg + 2) < SHEET) ? a2 : HOMEO;
            float v3 = (yok && (unsigned)(xg + 3) < SHEET) ? a3 : HOMEO;
            int c0 = yy * EWH + 2 * q;
            Ep[c0]               = v0;
            Ep[EP_HALF + c0]     = v1;
            Ep[c0 + 1]           = v2;
            Ep[EP_HALF + c0 + 1] = v3;
        }
        __syncthreads();

        // per-location 625-dot with register-resident bf16 weights
        #pragma unroll
        for (int s = 0; s < 10; ++s) {
            const int gbase = (s & 1) * EP_HALF + gb0 + (s >> 1);
            float acc = 0.f;
            #pragma unroll
            for (int k = 0; k < 5; ++k) {
                unsigned p = wpk[s][k];
                float e0 = Ep[gbase + offL[2*k]];
                float e1 = Ep[gbase + offL[2*k + 1]];
                acc = fmaf(e0, __uint_as_float(p << 16),         acc);
                acc = fmaf(e1, __uint_as_float(p & 0xffff0000u), acc);
            }
            acc = wred(acc);
            if (lane == 0) {
                float lat_neg = acc * isum_s[w*10 + s];
                float ec = Ep[gbase + 24*EWH + 12];
                float v = ec * 0.45f - lat_neg * 0.55f + aff_s[w*10 + s];
                v = tanhf(fmaxf(v, 0.f));
                dst[lbase + s] = v;
                lm_s[w*10 + s] += v;
            }
        }
        if (t < N_ITERS - 1) {
            __threadfence();
            grid.sync();
        }
    }

    // ================= publish lat_mean =================
    __syncthreads();
    for (int idx = tid; idx < LOCS; idx += BLK) {
        int r = idx / 20, cc = idx - 20 * r;
        ws[WS_LM + (i0 + r) * SHEET + (j0 + cc)] = lm_s[idx];
    }
    __threadfence();
    grid.sync();

    // ================= hebbian correlation =================
    // stage lat_mean tile (x0.1, pad HOMEO) into Ep (parity-split)
    for (int idx = tid; idx < EP_N; idx += BLK) {
        int p   = idx / EP_HALF;
        int rem = idx - p * EP_HALF;
        int yy  = rem / EWH;
        int col = rem - yy * EWH;
        int yg = i0 - 24 + yy;
        int xg = j0 - 24 + 2 * col + p;
        float v = HOMEO;
        if ((unsigned)yg < SHEET && (unsigned)xg < SHEET) v = ws[WS_LM + yg*SHEET + xg] * 0.1f;
        Ep[idx] = v;
    }
    __syncthreads();

    float wacc = 0.f;
    #pragma unroll
    for (int s = 0; s < 10; ++s) {
        const int gbase = (s & 1) * EP_HALF + gb0 + (s >> 1);
        float acc = 0.f;
        #pragma unroll
        for (int k = 0; k < 5; ++k) {
            unsigned p = wpk[s][k];
            float e0 = Ep[gbase + offL[2*k]];
            float e1 = Ep[gbase + offL[2*k + 1]];
            acc = fmaf(e0, __uint_as_float(p << 16),         acc);
            acc = fmaf(e1, __uint_as_float(p & 0xffff0000u), acc);
        }
        acc = wred(acc);
        if (lane == 0) {
            float lmv = lm_s[w*10 + s] * 0.1f;
            wacc += lmv * 62.5f * isum_s[w*10 + s] * acc;
        }
    }
    if (lane == 0) part_s[w] = wacc;
    __syncthreads();
    if (tid == 0) {
        float sm = 0.f;
        #pragma unroll
        for (int q = 0; q < NW; ++q) sm += part_s[q];
        ws[WS_PART + b] = sm;
    }
    __threadfence();
    grid.sync();

    // ================= deterministic final reduce (block 0) =================
    if (b == 0) {
        float v = (tid < GRID) ? ws[WS_PART + tid] : 0.f;
        Ep[tid] = v;
        if (tid < 1024 - BLK) Ep[BLK + tid] = 0.f;
        __syncthreads();
        #pragma unroll
        for (int s = 512; s > 0; s >>= 1) {
            if (tid < s) Ep[tid] += Ep[tid + s];
            __syncthreads();
        }
        if (tid == 0) out[2 * LTOT] = Ep[0];
    }
}

extern "C" void kernel_launch(void* const* d_in, const int* in_sizes, int n_in,
                              void* d_out, int out_size, void* d_ws, size_t ws_size,
                              hipStream_t stream) {
    const float* x    = (const float*)d_in[0];
    const float* rfs  = (const float*)d_in[1];
    const float* latw = (const float*)d_in[2];
    const float* ada  = (const float*)d_in[3];
    float* out = (float*)d_out;
    float* ws  = (float*)d_ws;

    void* args[] = { (void*)&x, (void*)&rfs, (void*)&latw, (void*)&ada,
                     (void*)&out, (void*)&ws };
    hipLaunchCooperativeKernel((void*)k_main, dim3(GRID), dim3(BLK),
                               args, 0, stream);
}